// Round 11
// baseline (46.317 us; speedup 1.0000x reference)
//
#include <hip/hip_runtime.h>

#define B_ 2048
#define V_ 2048
#define C_ 512
#define M_ 8
#define H_ 16
#define NB 2            // rows per compute block
#define CHUNK 256       // columns per compute block == blockDim.x
#define NCOMPUTE ((C_ / CHUNK) * (B_ / NB))   // 2048 compute blocks
#define NCOPY (B_ / 2)                        // 1024 copy blocks, 2 rows each

__device__ __forceinline__ float fast_exp2(float x) { return __builtin_amdgcn_exp2f(x); }
__device__ __forceinline__ float fast_rcp(float x)  { return __builtin_amdgcn_rcpf(x); }

// VALU-pipe reciprocal: int-magic seed (~3% rel err) + 2 Newton -> ~1e-6.
// Moves work OFF the saturated trans pipe onto the idle full-rate VALU pipe.
__device__ __forceinline__ float valu_rcp(float d) {
    float r = __uint_as_float(0x7EF311C3u - __float_as_uint(d));
    r = r * fmaf(-d, r, 2.0f);
    r = r * fmaf(-d, r, 2.0f);
    return r;
}

#define K_SCALE 2.885390081777927f      // 2*log2(e): tanh(x) = 1 - 2*rcp(exp2(K*x)+1)
#define LOG2E   1.4426950408889634f

__global__ __launch_bounds__(256) void grad_attn_kernel(
    const float* __restrict__ preds,
    const int*   __restrict__ mask_ids,
    const float* __restrict__ W1,
    const float* __restrict__ b1,
    const float* __restrict__ W2,
    float*       __restrict__ out)
{
    const int tid = threadIdx.x;
    const int bi  = blockIdx.x;

    if (bi >= NCOMPUTE) {
        // ---- pure copy region: cols [C_, V_) of 2 rows ----
        const int r0 = (bi - NCOMPUTE) * 2;
        #pragma unroll
        for (int r = 0; r < 2; ++r) {
            const float4* src = reinterpret_cast<const float4*>(preds + (size_t)(r0 + r) * V_ + C_);
            float4*       dst = reinterpret_cast<float4*>(out + (size_t)(r0 + r) * V_ + C_);
            #pragma unroll
            for (int j = tid; j < (V_ - C_) / 4; j += 256) dst[j] = src[j];
        }
        return;
    }

    const int chunk  = bi & 1;
    const int rowgrp = bi >> 1;
    const int b0 = rowgrp * NB;
    const int c  = chunk * CHUNK + tid;

    // ---- weights, K-prescaled; w2n = -2*w2 (base term cancels in softmax) ----
    float w1a[H_], w1b[H_], bb[H_], w2n[H_];
    {
        const float4* W1v = reinterpret_cast<const float4*>(W1 + (size_t)c * 2 * H_);
        const float4* b1v = reinterpret_cast<const float4*>(b1 + (size_t)c * H_);
        const float4* W2v = reinterpret_cast<const float4*>(W2 + (size_t)c * H_);
        #pragma unroll
        for (int i = 0; i < H_ / 4; ++i) {
            float4 a = W1v[i], bk = W1v[H_ / 4 + i], bv = b1v[i], wv = W2v[i];
            w1a[4*i+0] = a.x * K_SCALE;  w1a[4*i+1] = a.y * K_SCALE;
            w1a[4*i+2] = a.z * K_SCALE;  w1a[4*i+3] = a.w * K_SCALE;
            w1b[4*i+0] = bk.x * K_SCALE; w1b[4*i+1] = bk.y * K_SCALE;
            w1b[4*i+2] = bk.z * K_SCALE; w1b[4*i+3] = bk.w * K_SCALE;
            bb[4*i+0]  = bv.x * K_SCALE; bb[4*i+1]  = bv.y * K_SCALE;
            bb[4*i+2]  = bv.z * K_SCALE; bb[4*i+3]  = bv.w * K_SCALE;
            w2n[4*i+0] = -2.0f * wv.x;   w2n[4*i+1] = -2.0f * wv.y;
            w2n[4*i+2] = -2.0f * wv.z;   w2n[4*i+3] = -2.0f * wv.w;
        }
    }

    int midx[M_];
    {
        const int4* mi = reinterpret_cast<const int4*>(mask_ids + (size_t)c * M_);
        int4 a = mi[0], b = mi[1];
        midx[0] = a.x; midx[1] = a.y; midx[2] = a.z; midx[3] = a.w;
        midx[4] = b.x; midx[5] = b.y; midx[6] = b.z; midx[7] = b.w;
    }

    #pragma unroll
    for (int r = 0; r < NB; ++r) {
        const float* row = preds + (size_t)(b0 + r) * V_;
        const float ha = row[c];
        float hm[M_];
        #pragma unroll
        for (int m = 0; m < M_; ++m) hm[m] = row[midx[m]];

        float sc[M_];
        #pragma unroll
        for (int m = 0; m < M_; ++m) sc[m] = 0.0f;

        #pragma unroll
        for (int h = 0; h < H_; ++h) {
            const float pa  = fmaf(ha, w1a[h], bb[h]);
            const float wb  = w1b[h];
            const float w2h = w2n[h];
            #pragma unroll
            for (int m = 0; m < M_; ++m) {
                float e = fast_exp2(fmaf(hm[m], wb, pa));   // trans pipe
                float d = e + 1.0f;
                sc[m] = fmaf(valu_rcp(d), w2h, sc[m]);      // VALU pipe (no v_rcp)
            }
        }

        // softmax over M (uniform base term cancels; |sc| small -> exp2 safe)
        float ex[M_], sum = 0.0f, ws = 0.0f;
        #pragma unroll
        for (int m = 0; m < M_; ++m) {
            ex[m] = fast_exp2(sc[m] * LOG2E);
            sum += ex[m];
        }
        #pragma unroll
        for (int m = 0; m < M_; ++m) ws = fmaf(ex[m], hm[m], ws);
        float corrected = fmaxf(ha, fmaf(ws, fast_rcp(sum), 1e-6f));
        out[(size_t)(b0 + r) * V_ + c] = corrected;
    }
}

extern "C" void kernel_launch(void* const* d_in, const int* in_sizes, int n_in,
                              void* d_out, int out_size, void* d_ws, size_t ws_size,
                              hipStream_t stream) {
    const float* preds    = (const float*)d_in[0];
    const int*   mask_ids = (const int*)d_in[2];
    const float* W1       = (const float*)d_in[3];
    const float* b1       = (const float*)d_in[4];
    const float* W2       = (const float*)d_in[5];
    float* out = (float*)d_out;

    dim3 grid(NCOMPUTE + NCOPY);
    dim3 block(256);
    grad_attn_kernel<<<grid, block, 0, stream>>>(preds, mask_ids, W1, b1, W2, out);
}